// Round 11
// baseline (243.555 us; speedup 1.0000x reference)
//
#include <hip/hip_runtime.h>
#include <hip/hip_bf16.h>

// Fused QKV projection + 16-head self-attention. S=2048, B=2, H=1024, NH=16, DH=64.
// Inputs fp32, output fp32. bf16 internal compute (2% rel threshold).
//
// R11 = R8 skeleton (best attn: 72.5us) + one surgical change: V fragments are
// consumed DIRECTLY from vtb (global, A-operand layout — addressing verified in
// R10) instead of round-tripping through LDS. V loads issue before the staging
// barrier and are covered by S-MFMAs+softmax. LDS/block-kt: 104KB -> 64KB.
// R9/R10 lessons kept: staged K + barriers (latency), full MFMA density/wave.
//
// d_ws: qb[hb][s][d] 8MB | kb[hb][s][d] 8MB | vtb[hb][d][s] 8MB  (hb = h*2+b)

typedef __hip_bfloat16 bf16;
typedef __bf16 bfr;
typedef __attribute__((ext_vector_type(8))) __bf16 bf16x8;
typedef __attribute__((ext_vector_type(4))) __bf16 bf16x4;
typedef __attribute__((ext_vector_type(4))) float f32x4;

#define S_SEQ  2048
#define HID    1024
#define OUT3   3072
#define NROWS  4096
#define LSTR   72     // LDS row stride (bf16): 144 B — 16B-aligned

#if __has_builtin(__builtin_amdgcn_exp2f)
#define EXP2F(x) __builtin_amdgcn_exp2f(x)
#else
#define EXP2F(x) exp2f(x)
#endif

// q pre-scale: (1/sqrt(64)) * log2(e) -> scores in base-2 domain
#define QSCALE 0.18033688011112042f

// ---------------------------------------------------------------------------
// Fused cast: fp32 -> bf16 for X then W (verified R9/R10).
// ---------------------------------------------------------------------------
__global__ __launch_bounds__(256) void cast_both_kernel(
    const float* __restrict__ X, bfr* __restrict__ Xb,
    const float* __restrict__ W, bfr* __restrict__ Wb)
{
    int bid = blockIdx.x;
    const float* src;
    bfr* dst;
    int lid;
    if (bid < NROWS * HID / 2048) { src = X; dst = Xb; lid = bid; }
    else { src = W; dst = Wb; lid = bid - NROWS * HID / 2048; }
    int gid = lid * 256 + threadIdx.x;
    const float4* s4 = (const float4*)src;
    float4 a = s4[(size_t)gid * 2];
    float4 b = s4[(size_t)gid * 2 + 1];
    bf16x8 v;
    v[0] = (bfr)a.x; v[1] = (bfr)a.y; v[2] = (bfr)a.z; v[3] = (bfr)a.w;
    v[4] = (bfr)b.x; v[5] = (bfr)b.y; v[6] = (bfr)b.z; v[7] = (bfr)b.w;
    *(bf16x8*)(dst + (size_t)gid * 8) = v;
}

// ---------------------------------------------------------------------------
// MFMA GEMM (m97 recipe, unchanged from R8). Epilogue splits into
// qb (pre-scaled by QSCALE), kb, vtb.
// ---------------------------------------------------------------------------
__device__ __forceinline__ void gload_lds16(const void* g, void* l) {
    __builtin_amdgcn_global_load_lds(
        (const __attribute__((address_space(1))) unsigned int*)g,
        (__attribute__((address_space(3))) unsigned int*)l, 16, 0, 0);
}

__global__ __launch_bounds__(256, 3) void qkv_gemm_mfma(
    const bfr* __restrict__ Xb, const bfr* __restrict__ Wb,
    const float* __restrict__ bias,
    bfr* __restrict__ qb, bfr* __restrict__ kb, bfr* __restrict__ vtb)
{
    __shared__ __attribute__((aligned(16))) bfr As[128 * 64];
    __shared__ __attribute__((aligned(16))) bfr Bs[128 * 64];

    const int o0 = blockIdx.x * 128;
    const int r0 = blockIdx.y * 128;
    const int tid = threadIdx.x;
    const int lane = tid & 63;
    const int w = tid >> 6;
    const int l15 = lane & 15;
    const int quad = lane >> 4;
    const int m0 = (w & 1) * 64;
    const int n0 = (w >> 1) * 64;

    f32x4 acc[4][4];
#pragma unroll
    for (int mi = 0; mi < 4; mi++)
#pragma unroll
        for (int ni = 0; ni < 4; ni++) acc[mi][ni] = {0.f, 0.f, 0.f, 0.f};

    for (int k0 = 0; k0 < HID; k0 += 64) {
#pragma unroll
        for (int i = 0; i < 4; i++) {
            int c = i * 256 + tid;
            int row = c >> 3, c8 = c & 7;
            gload_lds16(Xb + (size_t)(r0 + row) * HID + k0 + c8 * 8, As + c * 8);
            gload_lds16(Wb + (size_t)(o0 + row) * HID + k0 + c8 * 8, Bs + c * 8);
        }
        __syncthreads();

#pragma unroll
        for (int ks = 0; ks < 2; ks++) {
            bf16x8 af[4], bfg[4];
#pragma unroll
            for (int mi = 0; mi < 4; mi++)
                af[mi] = *(const bf16x8*)(As + (m0 + mi * 16 + l15) * 64 + ks * 32 + quad * 8);
#pragma unroll
            for (int ni = 0; ni < 4; ni++)
                bfg[ni] = *(const bf16x8*)(Bs + (n0 + ni * 16 + l15) * 64 + ks * 32 + quad * 8);
#pragma unroll
            for (int mi = 0; mi < 4; mi++)
#pragma unroll
                for (int ni = 0; ni < 4; ni++)
                    acc[mi][ni] = __builtin_amdgcn_mfma_f32_16x16x32_bf16(
                        af[mi], bfg[ni], acc[mi][ni], 0, 0, 0);
        }
        __syncthreads();
    }

#pragma unroll
    for (int ni = 0; ni < 4; ni++) {
        int cb = o0 + n0 + ni * 16;
        int h = cb / 192;
        int rem = cb % 192;
        int t = rem >> 6;
        int d = (rem & 63) + l15;
        float bv = bias[cb + l15];
#pragma unroll
        for (int mi = 0; mi < 4; mi++) {
#pragma unroll
            for (int r = 0; r < 4; r++) {
                int gr = r0 + m0 + mi * 16 + quad * 4 + r;
                int s = gr >> 1, b = gr & 1;
                int hb = h * 2 + b;
                float val = acc[mi][ni][r] + bv;
                if (t == 0)
                    qb[((size_t)hb * S_SEQ + s) * 64 + d] = (bfr)(val * QSCALE);
                else if (t == 1)
                    kb[((size_t)hb * S_SEQ + s) * 64 + d] = (bfr)val;
                else
                    vtb[((size_t)hb * 64 + d) * S_SEQ + s] = (bfr)val;
            }
        }
    }
}

// ---------------------------------------------------------------------------
// Attention R11: R8's attn4 with V direct-from-global fragments (no Vts LDS).
// Block = 4 waves = (64-q tile, hb). Per 64-key tile: stage K to LDS (reg-
// prefetched), V frags issued pre-barrier and consumed after S+softmax.
// Layouts (verified R4-R10): A[m=l15][k=quad*8+j], B[k=quad*8+j][n=l15],
// C/D col=l15(n), row=quad*4+reg(m).
// ---------------------------------------------------------------------------
__global__ __launch_bounds__(256, 4) void attn7_kernel(
    const bfr* __restrict__ qb, const bfr* __restrict__ kb,
    const bfr* __restrict__ vtb, float* __restrict__ out)
{
    __shared__ __attribute__((aligned(16))) bfr Ks [64 * LSTR];  // [key][d]
    __shared__ __attribute__((aligned(16))) bfr Ptq[64 * LSTR];  // [q][key], wave-private rows

    const int qt = blockIdx.x;
    const int hb = blockIdx.y;
    const int h = hb >> 1, b = hb & 1;
    const int tid = threadIdx.x;
    const int lane = tid & 63;
    const int w = tid >> 6;
    const int l15 = lane & 15;
    const int quad = lane >> 4;
    const size_t hboff = (size_t)hb * S_SEQ * 64;

    // K staging coords (as R8): thread covers rows srow0, srow0+32; 16B chunk sc8.
    const int srow0 = tid >> 3;
    const int sc8   = tid & 7;
    // Q fragments (B-operand), loaded once; pre-scaled by QSCALE in GEMM.
    const int qrow = qt * 64 + 16 * w + l15;
    bf16x8 qf[2];
    qf[0] = *(const bf16x8*)(qb + hboff + (size_t)qrow * 64 + quad * 8);
    qf[1] = *(const bf16x8*)(qb + hboff + (size_t)qrow * 64 + quad * 8 + 32);

    f32x4 Oacc[4];
#pragma unroll
    for (int mt = 0; mt < 4; mt++) Oacc[mt] = {0.f, 0.f, 0.f, 0.f};
    float l_st = 0.f;

    // Prefetch K tile 0 into staging registers.
    bf16x8 kr[2];
#pragma unroll
    for (int p = 0; p < 2; p++)
        kr[p] = *(const bf16x8*)(kb + hboff + (size_t)(srow0 + p * 32) * 64 + sc8 * 8);

    for (int kt = 0; kt < 32; kt++) {
        __syncthreads();   // previous compute done reading Ks
#pragma unroll
        for (int p = 0; p < 2; p++)
            *(bf16x8*)(Ks + (srow0 + p * 32) * LSTR + sc8 * 8) = kr[p];
        // Next K tile -> staging regs (latency drains during this iter's compute).
        {
            int ktn = kt + 1 < 32 ? kt + 1 : 31;
#pragma unroll
            for (int p = 0; p < 2; p++)
                kr[p] = *(const bf16x8*)(kb + hboff +
                    (size_t)(ktn * 64 + srow0 + p * 32) * 64 + sc8 * 8);
        }
        // This tile's V fragments, direct global->reg (A-operand layout, per
        // R10-verified addressing). Consumed after S+softmax (~400 cyc cover).
        bf16x8 vf[4][2];
#pragma unroll
        for (int ks = 0; ks < 2; ks++)
#pragma unroll
            for (int mt = 0; mt < 4; mt++)
                vf[mt][ks] = *(const bf16x8*)(vtb + hboff +
                    (size_t)(mt * 16 + l15) * S_SEQ + kt * 64 + quad * 8 + 32 * ks);
        __syncthreads();   // Ks visible

        // --- S^T = K Q^T (base-2 domain) ---
        f32x4 sc[4];
#pragma unroll
        for (int mt = 0; mt < 4; mt++) sc[mt] = {0.f, 0.f, 0.f, 0.f};
#pragma unroll
        for (int k0 = 0; k0 < 2; k0++) {
#pragma unroll
            for (int mt = 0; mt < 4; mt++) {
                bf16x8 kf = *(const bf16x8*)(Ks + (mt * 16 + l15) * LSTR + quad * 8 + 32 * k0);
                sc[mt] = __builtin_amdgcn_mfma_f32_16x16x32_bf16(kf, qf[k0], sc[mt], 0, 0, 0);
            }
        }

        // --- p = 2^s (no max: |s| bounded ~4); pack P^T q-major ---
        float rs = 0.f;
#pragma unroll
        for (int mt = 0; mt < 4; mt++) {
            bf16x4 pk;
#pragma unroll
            for (int r = 0; r < 4; r++) {
                float pv = EXP2F(sc[mt][r]);
                rs += pv;
                pk[r] = (bfr)pv;
            }
            *(bf16x4*)(Ptq + (16 * w + l15) * LSTR + mt * 16 + quad * 4) = pk;
        }
        rs += __shfl_xor(rs, 16);
        rs += __shfl_xor(rs, 32);
        l_st += rs;

        // --- O^T += V^T P^T (Ptq rows wave-private: no barrier; V from regs) ---
#pragma unroll
        for (int k0 = 0; k0 < 2; k0++) {
            bf16x8 pf = *(const bf16x8*)(Ptq + (16 * w + l15) * LSTR + quad * 8 + 32 * k0);
#pragma unroll
            for (int mt = 0; mt < 4; mt++)
                Oacc[mt] = __builtin_amdgcn_mfma_f32_16x16x32_bf16(
                    vf[mt][k0], pf, Oacc[mt], 0, 0, 0);
        }
    }

    // --- epilogue: O^T[d][q] -> out[s][b][h*64+d], float4 stores ---
    float inv = 1.0f / l_st;
    float* orow = out + ((size_t)qrow * 2 + b) * HID + h * 64;
#pragma unroll
    for (int mt = 0; mt < 4; mt++) {
        float4 o4;
        o4.x = Oacc[mt][0] * inv;
        o4.y = Oacc[mt][1] * inv;
        o4.z = Oacc[mt][2] * inv;
        o4.w = Oacc[mt][3] * inv;
        *(float4*)(orow + mt * 16 + quad * 4) = o4;
    }
}

// ---------------------------------------------------------------------------
extern "C" void kernel_launch(void* const* d_in, const int* in_sizes, int n_in,
                              void* d_out, int out_size, void* d_ws, size_t ws_size,
                              hipStream_t stream) {
    const float* X    = (const float*)d_in[0];
    const float* W    = (const float*)d_in[1];
    const float* bias = (const float*)d_in[2];
    float* out = (float*)d_out;

    bfr* qb  = (bfr*)d_ws;
    bfr* kb  = qb + (size_t)32 * S_SEQ * 64;
    bfr* vtb = kb + (size_t)32 * S_SEQ * 64;

    // d_out as cast scratch (14.7 MB <= 16.8 MB); attention overwrites it last.
    bfr* Xb = (bfr*)d_out;
    bfr* Wb = Xb + (size_t)NROWS * HID;

    cast_both_kernel<<<(NROWS * HID + OUT3 * HID) / 2048, 256, 0, stream>>>(X, Xb, W, Wb);

    dim3 g1(OUT3 / 128, NROWS / 128);
    qkv_gemm_mfma<<<g1, 256, 0, stream>>>(Xb, Wb, bias, qb, kb, vtb);

    dim3 g2(S_SEQ / 64, 32);                    // 32 x 32 = 1024 blocks
    attn7_kernel<<<g2, 256, 0, stream>>>(qb, kb, vtb, out);
}

// Round 12
// 173.808 us; speedup vs baseline: 1.4013x; 1.4013x over previous
//
#include <hip/hip_runtime.h>
#include <hip/hip_bf16.h>

// Fused QKV projection + 16-head self-attention. S=2048, B=2, H=1024, NH=16, DH=64.
// Inputs fp32, output fp32. bf16 internal compute (2% rel threshold).
//
// R12: R8 attention restored verbatim (72.5us — best of 6 attn variants;
// R9/R10/R11 all regressed by trading latency-hiding or coalescing for LDS
// bytes). This round: GEMM epilogue vtb stores coalesced via LDS transpose
// (was 2B scalars at 4KB stride = ~64 cache lines/instr); casts fused.
//
// d_ws: qb[hb][s][d] 8MB | kb[hb][s][d] 8MB | vtb[hb][d][s] 8MB  (hb = h*2+b)

typedef __hip_bfloat16 bf16;
typedef __bf16 bfr;
typedef __attribute__((ext_vector_type(8))) __bf16 bf16x8;
typedef __attribute__((ext_vector_type(4))) __bf16 bf16x4;
typedef __attribute__((ext_vector_type(4))) float f32x4;

#define S_SEQ  2048
#define HID    1024
#define OUT3   3072
#define NROWS  4096
#define LSTR   72     // attn LDS row stride (bf16): 144 B

#if __has_builtin(__builtin_amdgcn_exp2f)
#define EXP2F(x) __builtin_amdgcn_exp2f(x)
#else
#define EXP2F(x) exp2f(x)
#endif

// q pre-scale: (1/sqrt(64)) * log2(e) -> scores in base-2 domain
#define QSCALE 0.18033688011112042f

// ---------------------------------------------------------------------------
// Fused cast: fp32 -> bf16 for X then W (verified R9/R10).
// ---------------------------------------------------------------------------
__global__ __launch_bounds__(256) void cast_both_kernel(
    const float* __restrict__ X, bfr* __restrict__ Xb,
    const float* __restrict__ W, bfr* __restrict__ Wb)
{
    int bid = blockIdx.x;
    const float* src;
    bfr* dst;
    int lid;
    if (bid < NROWS * HID / 2048) { src = X; dst = Xb; lid = bid; }
    else { src = W; dst = Wb; lid = bid - NROWS * HID / 2048; }
    int gid = lid * 256 + threadIdx.x;
    const float4* s4 = (const float4*)src;
    float4 a = s4[(size_t)gid * 2];
    float4 b = s4[(size_t)gid * 2 + 1];
    bf16x8 v;
    v[0] = (bfr)a.x; v[1] = (bfr)a.y; v[2] = (bfr)a.z; v[3] = (bfr)a.w;
    v[4] = (bfr)b.x; v[5] = (bfr)b.y; v[6] = (bfr)b.z; v[7] = (bfr)b.w;
    *(bf16x8*)(dst + (size_t)gid * 8) = v;
}

// ---------------------------------------------------------------------------
// MFMA GEMM (m97 recipe). Epilogue: qb (pre-scaled), kb stored directly
// (32B-contiguous per 16 lanes); vtb (V^T, the 4KB-stride case) goes through
// an LDS transpose reusing the As/Bs region, then coalesced bf16x8 stores.
// ---------------------------------------------------------------------------
__device__ __forceinline__ void gload_lds16(const void* g, void* l) {
    __builtin_amdgcn_global_load_lds(
        (const __attribute__((address_space(1))) unsigned int*)g,
        (__attribute__((address_space(3))) unsigned int*)l, 16, 0, 0);
}

__global__ __launch_bounds__(256, 3) void qkv_gemm_mfma(
    const bfr* __restrict__ Xb, const bfr* __restrict__ Wb,
    const float* __restrict__ bias,
    bfr* __restrict__ qb, bfr* __restrict__ kb, bfr* __restrict__ vtb)
{
    __shared__ __attribute__((aligned(16))) unsigned char lds_all[32768];
    bfr* As = (bfr*)lds_all;              // 128x64 bf16 = 16384 B
    bfr* Bs = (bfr*)(lds_all + 16384);    // 128x64 bf16 = 16384 B
    bfr* Tr = (bfr*)lds_all;              // epilogue V^T buf: 64 x 144 = 18432 B

    const int o0 = blockIdx.x * 128;
    const int r0 = blockIdx.y * 128;
    const int tid = threadIdx.x;
    const int lane = tid & 63;
    const int w = tid >> 6;
    const int l15 = lane & 15;
    const int quad = lane >> 4;
    const int m0 = (w & 1) * 64;
    const int n0 = (w >> 1) * 64;

    f32x4 acc[4][4];
#pragma unroll
    for (int mi = 0; mi < 4; mi++)
#pragma unroll
        for (int ni = 0; ni < 4; ni++) acc[mi][ni] = {0.f, 0.f, 0.f, 0.f};

    for (int k0 = 0; k0 < HID; k0 += 64) {
#pragma unroll
        for (int i = 0; i < 4; i++) {
            int c = i * 256 + tid;
            int row = c >> 3, c8 = c & 7;
            gload_lds16(Xb + (size_t)(r0 + row) * HID + k0 + c8 * 8, As + c * 8);
            gload_lds16(Wb + (size_t)(o0 + row) * HID + k0 + c8 * 8, Bs + c * 8);
        }
        __syncthreads();

#pragma unroll
        for (int ks = 0; ks < 2; ks++) {
            bf16x8 af[4], bfg[4];
#pragma unroll
            for (int mi = 0; mi < 4; mi++)
                af[mi] = *(const bf16x8*)(As + (m0 + mi * 16 + l15) * 64 + ks * 32 + quad * 8);
#pragma unroll
            for (int ni = 0; ni < 4; ni++)
                bfg[ni] = *(const bf16x8*)(Bs + (n0 + ni * 16 + l15) * 64 + ks * 32 + quad * 8);
#pragma unroll
            for (int mi = 0; mi < 4; mi++)
#pragma unroll
                for (int ni = 0; ni < 4; ni++)
                    acc[mi][ni] = __builtin_amdgcn_mfma_f32_16x16x32_bf16(
                        af[mi], bfg[ni], acc[mi][ni], 0, 0, 0);
        }
        __syncthreads();   // also makes As/Bs safe to reuse as Tr after loop
    }

    // --- epilogue. C/D layout: col=l15, row=quad*4+r.
    // o0%192==0 : cols are q|k only. ==64: waves 2,3 hold the V tile.
    // ==128: waves 0,1 hold the V tile. V tile always spans d 0..63 x gr 0..127.
    const int omod = o0 % 192;
#pragma unroll
    for (int ni = 0; ni < 4; ni++) {
        int cb = o0 + n0 + ni * 16;
        int h = cb / 192;
        int rem = cb % 192;
        int t = rem >> 6;
        int d = (rem & 63) + l15;
        float bv = bias[cb + l15];
        if (t == 2) {
            // stash V^T into LDS: Tr[d][ (grl&1)*72 + (grl>>1) ]
#pragma unroll
            for (int mi = 0; mi < 4; mi++)
#pragma unroll
                for (int r = 0; r < 4; r++) {
                    int grl = m0 + mi * 16 + quad * 4 + r;   // 0..127
                    Tr[(size_t)d * 144 + (grl & 1) * 72 + (grl >> 1)]
                        = (bfr)(acc[mi][ni][r] + bv);
                }
        } else {
#pragma unroll
            for (int mi = 0; mi < 4; mi++)
#pragma unroll
                for (int r = 0; r < 4; r++) {
                    int gr = r0 + m0 + mi * 16 + quad * 4 + r;
                    int s = gr >> 1, b = gr & 1;
                    int hb = h * 2 + b;
                    float val = acc[mi][ni][r] + bv;
                    if (t == 0)
                        qb[((size_t)hb * S_SEQ + s) * 64 + d] = (bfr)(val * QSCALE);
                    else
                        kb[((size_t)hb * S_SEQ + s) * 64 + d] = (bfr)val;
                }
        }
    }
    if (omod != 0) {          // block-uniform: this block produced a V tile
        __syncthreads();      // Tr writes visible
        int ht = (omod == 64) ? (o0 + 64) / 192 : o0 / 192;
        int d = tid >> 2;
        int b = (tid >> 1) & 1;
        int chunk = tid & 1;            // 32-s half
        int s0 = r0 >> 1;               // r0 is a multiple of 128 -> s0 of 64
        int hb = ht * 2 + b;
        const bfr* src = Tr + (size_t)d * 144 + b * 72 + chunk * 32;
        bfr* dstp = vtb + ((size_t)hb * 64 + d) * S_SEQ + s0 + chunk * 32;
#pragma unroll
        for (int j = 0; j < 4; j++)
            *(bf16x8*)(dstp + j * 8) = *(const bf16x8*)(src + j * 8);
    }
}

// ---------------------------------------------------------------------------
// Attention (R8's attn4, restored verbatim — 72.5us best). Block = 4 waves =
// (64-q tile, hb). Staged K (reg-prefetched) + staged V^T; no-max exp2
// softmax; wave-private P round-trip; 2 barriers/kt.
// Layouts (verified R4-R11): A[m=l15][k=quad*8+j], B[k=quad*8+j][n=l15],
// C/D col=l15(n), row=quad*4+reg(m).
// ---------------------------------------------------------------------------
__global__ __launch_bounds__(256, 4) void attn4_kernel(
    const bfr* __restrict__ qb, const bfr* __restrict__ kb,
    const bfr* __restrict__ vtb, float* __restrict__ out)
{
    __shared__ __attribute__((aligned(16))) bfr Ks [64 * LSTR];  // [key][d]
    __shared__ __attribute__((aligned(16))) bfr Vts[64 * LSTR];  // [d][key]
    __shared__ __attribute__((aligned(16))) bfr Ptq[64 * LSTR];  // [q][key], wave-private rows

    const int qt = blockIdx.x;
    const int hb = blockIdx.y;
    const int h = hb >> 1, b = hb & 1;
    const int tid = threadIdx.x;
    const int lane = tid & 63;
    const int w = tid >> 6;
    const int l15 = lane & 15;
    const int quad = lane >> 4;
    const size_t hboff = (size_t)hb * S_SEQ * 64;

    const int srow0 = tid >> 3;          // staging row (0..31), +32 for p=1
    const int sc8   = tid & 7;           // 16B chunk
    const int qrow = qt * 64 + 16 * w + l15;
    bf16x8 qf[2];
    qf[0] = *(const bf16x8*)(qb + hboff + (size_t)qrow * 64 + quad * 8);
    qf[1] = *(const bf16x8*)(qb + hboff + (size_t)qrow * 64 + quad * 8 + 32);

    f32x4 Oacc[4];
#pragma unroll
    for (int mt = 0; mt < 4; mt++) Oacc[mt] = {0.f, 0.f, 0.f, 0.f};
    float l_st = 0.f;

    // Prefetch tile 0 into registers.
    bf16x8 kr[2], vr[2];
#pragma unroll
    for (int p = 0; p < 2; p++) {
        int row = srow0 + p * 32;
        kr[p] = *(const bf16x8*)(kb + hboff + (size_t)row * 64 + sc8 * 8);
        vr[p] = *(const bf16x8*)(vtb + hboff + (size_t)row * S_SEQ + sc8 * 8);
    }

    for (int kt = 0; kt < 32; kt++) {
        __syncthreads();   // previous compute done reading Ks/Vts
#pragma unroll
        for (int p = 0; p < 2; p++) {
            int row = srow0 + p * 32;
            *(bf16x8*)(Ks  + row * LSTR + sc8 * 8) = kr[p];
            *(bf16x8*)(Vts + row * LSTR + sc8 * 8) = vr[p];
        }
        // Issue next tile's global loads; latency overlaps compute below.
        {
            int ktn = kt + 1 < 32 ? kt + 1 : 31;
#pragma unroll
            for (int p = 0; p < 2; p++) {
                int row = srow0 + p * 32;
                kr[p] = *(const bf16x8*)(kb + hboff + (size_t)(ktn * 64 + row) * 64 + sc8 * 8);
                vr[p] = *(const bf16x8*)(vtb + hboff + (size_t)row * S_SEQ + ktn * 64 + sc8 * 8);
            }
        }
        __syncthreads();   // Ks/Vts visible

        // --- S^T = K Q^T (base-2 domain) ---
        f32x4 sc[4];
#pragma unroll
        for (int mt = 0; mt < 4; mt++) sc[mt] = {0.f, 0.f, 0.f, 0.f};
#pragma unroll
        for (int k0 = 0; k0 < 2; k0++) {
#pragma unroll
            for (int mt = 0; mt < 4; mt++) {
                bf16x8 kf = *(const bf16x8*)(Ks + (mt * 16 + l15) * LSTR + quad * 8 + 32 * k0);
                sc[mt] = __builtin_amdgcn_mfma_f32_16x16x32_bf16(kf, qf[k0], sc[mt], 0, 0, 0);
            }
        }

        // --- p = 2^s (no max: |s| bounded ~4); pack P^T q-major ---
        float rs = 0.f;
#pragma unroll
        for (int mt = 0; mt < 4; mt++) {
            bf16x4 pk;
#pragma unroll
            for (int r = 0; r < 4; r++) {
                float pv = EXP2F(sc[mt][r]);
                rs += pv;
                pk[r] = (bfr)pv;
            }
            *(bf16x4*)(Ptq + (16 * w + l15) * LSTR + mt * 16 + quad * 4) = pk;
        }
        rs += __shfl_xor(rs, 16);
        rs += __shfl_xor(rs, 32);
        l_st += rs;

        // --- O^T += V^T P^T (Ptq rows wave-private: no barrier) ---
#pragma unroll
        for (int k0 = 0; k0 < 2; k0++) {
            bf16x8 pf = *(const bf16x8*)(Ptq + (16 * w + l15) * LSTR + quad * 8 + 32 * k0);
#pragma unroll
            for (int mt = 0; mt < 4; mt++) {
                bf16x8 vf = *(const bf16x8*)(Vts + (mt * 16 + l15) * LSTR + quad * 8 + 32 * k0);
                Oacc[mt] = __builtin_amdgcn_mfma_f32_16x16x32_bf16(vf, pf, Oacc[mt], 0, 0, 0);
            }
        }
    }

    // --- epilogue: O^T[d][q] -> out[s][b][h*64+d], float4 stores ---
    float inv = 1.0f / l_st;
    float* orow = out + ((size_t)qrow * 2 + b) * HID + h * 64;
#pragma unroll
    for (int mt = 0; mt < 4; mt++) {
        float4 o4;
        o4.x = Oacc[mt][0] * inv;
        o4.y = Oacc[mt][1] * inv;
        o4.z = Oacc[mt][2] * inv;
        o4.w = Oacc[mt][3] * inv;
        *(float4*)(orow + mt * 16 + quad * 4) = o4;
    }
}

// ---------------------------------------------------------------------------
extern "C" void kernel_launch(void* const* d_in, const int* in_sizes, int n_in,
                              void* d_out, int out_size, void* d_ws, size_t ws_size,
                              hipStream_t stream) {
    const float* X    = (const float*)d_in[0];
    const float* W    = (const float*)d_in[1];
    const float* bias = (const float*)d_in[2];
    float* out = (float*)d_out;

    bfr* qb  = (bfr*)d_ws;
    bfr* kb  = qb + (size_t)32 * S_SEQ * 64;
    bfr* vtb = kb + (size_t)32 * S_SEQ * 64;

    // d_out as cast scratch (14.7 MB <= 16.8 MB); attention overwrites it last.
    bfr* Xb = (bfr*)d_out;
    bfr* Wb = Xb + (size_t)NROWS * HID;

    cast_both_kernel<<<(NROWS * HID + OUT3 * HID) / 2048, 256, 0, stream>>>(X, Xb, W, Wb);

    dim3 g1(OUT3 / 128, NROWS / 128);           // 24 x 32 = 768 blocks
    qkv_gemm_mfma<<<g1, 256, 0, stream>>>(Xb, Wb, bias, qb, kb, vtb);

    dim3 g2(S_SEQ / 64, 32);                    // 32 x 32 = 1024 blocks
    attn4_kernel<<<g2, 256, 0, stream>>>(qb, kb, vtb, out);
}